// Round 4
// baseline (362.351 us; speedup 1.0000x reference)
//
#include <hip/hip_runtime.h>

typedef _Float16 f16;
typedef f16 f16x8 __attribute__((ext_vector_type(8)));
typedef f16 f16x4 __attribute__((ext_vector_type(4)));
typedef float f32x4 __attribute__((ext_vector_type(4)));

#define NB 32
#define NC 256
#define NP 8
#define NHW 4096

// ---- workspace byte offsets ----
#define AH_OFF 0u         // A_hi f16 [256][256]
#define AL_OFF 131072u    // A_lo f16 [256][256] (x512 scaled)
#define CV_OFF 262144u    // cvec f32 [256]
#define PV_OFF 263168u    // pvec_t f32 [B][16][256][8] = 4 MB
#define PS_OFF 4457472u   // psw_t  f32 [B][16][8]
// end ~4.47 MB

// ---- k_fused LDS geometry (bytes) ----
#define XS_PITCH 528      // per s-row: 256 f16 data + pad; 16B-aligned rows
#define XS_LO    33792    // lo region base (64 * 528)
#define DP_OFF   67584    // dpart f32 [4][8][64] = 8 KB
#define MLS_OFF  75776    // mls f32: 64 rows * 16 dwords = 4 KB
#define SMEM_BYTES 79872  // 2 blocks/CU (159744 <= 160 KiB)

#define SWZ(s) ((((s) >> 2) & 7) << 4)   // 16B-granular XOR swizzle key

#define MFMA16(a, b, c) __builtin_amdgcn_mfma_f32_16x16x32_f16(a, b, c, 0, 0, 0)

// Fold BN into conv1; split folded weight into f16 hi + (lo*512).
__global__ __launch_bounds__(256) void k_prep(
    const float* __restrict__ W1, const float* __restrict__ b1,
    const float* __restrict__ gamma, const float* __restrict__ beta,
    const float* __restrict__ mean, const float* __restrict__ var,
    f16* __restrict__ Ah, f16* __restrict__ Al, float* __restrict__ cvec) {
  const int o = blockIdx.x;
  const int k = threadIdx.x;
  const float inv = gamma[o] * rsqrtf(var[o] + 1e-5f);
  const float a = W1[o * NC + k] * inv;
  const f16 hi = (f16)a;
  Ah[o * NC + k] = hi;
  Al[o * NC + k] = (f16)((a - (float)hi) * 512.0f);
  if (k == 0) cvec[o] = (b1[o] - mean[o]) * inv + beta[o];
}

// Fused: conv1(MFMA f16 hi/lo)+BN+ReLU + conv2+sigmoid + vec contraction.
// Block = (batch, tile-group of 4 x 64-spatial tiles); 4 waves; 2 blocks/CU.
__global__ __launch_bounds__(256, 2) void k_fused(
    const float* __restrict__ x, const f16* __restrict__ Ah,
    const f16* __restrict__ Al, const float* __restrict__ cvec,
    const float* __restrict__ W2, const float* __restrict__ b2,
    float* __restrict__ pvec_t, float* __restrict__ psw_t) {
  extern __shared__ __align__(16) char sm[];
  const int b  = blockIdx.x >> 4;
  const int tg = blockIdx.x & 15;
  const int t  = threadIdx.x;
  const int w    = t >> 6;   // wave: o-slice base w*64
  const int lane = t & 63;
  const int lg = lane >> 4;  // k-group
  const int ln = lane & 15;  // m (A-row) / n (s-col)
  const int cb = t >> 2;     // vec phase: channel block (4 ch)
  const int sq = t & 3;      // vec phase: s quarter (16 s)

  float accv[4][8];          // vec partials [c-sub][p], persist across tiles
  float smac[8];             // sum_w partials
  #pragma unroll
  for (int j = 0; j < 4; ++j)
    #pragma unroll
    for (int p = 0; p < 8; ++p) accv[j][p] = 0.f;
  #pragma unroll
  for (int p = 0; p < 8; ++p) smac[p] = 0.f;

  for (int tt = 0; tt < 4; ++tt) {
    const int hw0 = (tg * 4 + tt) * 64;
    __syncthreads();  // protect xs/mls/dpart from previous iteration's readers

    // ---- stage x tile: [256c][64s] f32 -> LDS transposed f16 hi/lo, swizzled ----
    {
      const float* xb = x + (size_t)b * NC * NHW + hw0;
      #pragma unroll
      for (int i = 0; i < 4; ++i) {
        const int id = i * 256 + t;
        const int cbs = id >> 4;   // channel block (4 ch)
        const int sb  = id & 15;   // spatial block (4 s)
        const float* r0 = xb + (size_t)(cbs * 4) * NHW + sb * 4;
        const float4 v0 = *(const float4*)(r0);
        const float4 v1 = *(const float4*)(r0 + NHW);
        const float4 v2 = *(const float4*)(r0 + 2 * NHW);
        const float4 v3 = *(const float4*)(r0 + 3 * NHW);
        #pragma unroll
        for (int j = 0; j < 4; ++j) {
          const float e0 = ((const float*)&v0)[j];
          const float e1 = ((const float*)&v1)[j];
          const float e2 = ((const float*)&v2)[j];
          const float e3 = ((const float*)&v3)[j];
          const f16 h0 = (f16)e0, h1 = (f16)e1, h2 = (f16)e2, h3 = (f16)e3;
          const f16 l0 = (f16)((e0 - (float)h0) * 512.0f);
          const f16 l1 = (f16)((e1 - (float)h1) * 512.0f);
          const f16 l2 = (f16)((e2 - (float)h2) * 512.0f);
          const f16 l3 = (f16)((e3 - (float)h3) * 512.0f);
          const int s = sb * 4 + j;
          char* dst = sm + s * XS_PITCH + ((cbs * 8) ^ SWZ(s));
          *(f16x4*)dst = (f16x4){h0, h1, h2, h3};
          *(f16x4*)(dst + XS_LO) = (f16x4){l0, l1, l2, l3};
        }
      }
    }
    __syncthreads();

    // ---- GEMM: h[o][s] = sum_c A[o][c]*x[c][s]; wave owns o in [w*64, w*64+64) ----
    f32x4 acc1[4][4] = {};   // hi*hi
    f32x4 acc2[4][4] = {};   // hi*lo + lo*hi (x512)
    #pragma unroll 1
    for (int k0 = 0; k0 < 8; ++k0) {
      f16x8 ah[4], al[4], xh[4], xl[4];
      #pragma unroll
      for (int mi = 0; mi < 4; ++mi) {
        const size_t off = (size_t)((w * 64 + mi * 16 + ln) * NC + k0 * 32 + lg * 8);
        ah[mi] = *(const f16x8*)(Ah + off);
        al[mi] = *(const f16x8*)(Al + off);
      }
      #pragma unroll
      for (int nf = 0; nf < 4; ++nf) {
        const int s = nf * 16 + ln;
        const char* p = sm + s * XS_PITCH + ((k0 * 64 + lg * 16) ^ SWZ(s));
        xh[nf] = *(const f16x8*)(p);
        xl[nf] = *(const f16x8*)(p + XS_LO);
      }
      #pragma unroll
      for (int mi = 0; mi < 4; ++mi)
        #pragma unroll
        for (int nf = 0; nf < 4; ++nf)
          acc1[mi][nf] = MFMA16(ah[mi], xh[nf], acc1[mi][nf]);
      #pragma unroll
      for (int mi = 0; mi < 4; ++mi)
        #pragma unroll
        for (int nf = 0; nf < 4; ++nf)
          acc2[mi][nf] = MFMA16(ah[mi], xl[nf], acc2[mi][nf]);
      #pragma unroll
      for (int mi = 0; mi < 4; ++mi)
        #pragma unroll
        for (int nf = 0; nf < 4; ++nf)
          acc2[mi][nf] = MFMA16(al[mi], xh[nf], acc2[mi][nf]);
    }

    // ---- bias + ReLU in-register; conv2 partials per lane ----
    {
      f32x4 cv[4];
      #pragma unroll
      for (int mi = 0; mi < 4; ++mi)
        cv[mi] = *(const f32x4*)(cvec + w * 64 + mi * 16 + lg * 4);
      #pragma unroll
      for (int mi = 0; mi < 4; ++mi)
        #pragma unroll
        for (int nf = 0; nf < 4; ++nf)
          #pragma unroll
          for (int r = 0; r < 4; ++r) {
            const float v = acc1[mi][nf][r] + acc2[mi][nf][r] * (1.0f / 512.0f) + cv[mi][r];
            acc1[mi][nf][r] = v > 0.0f ? v : 0.0f;  // h
          }

      float pd[8][4] = {};  // [p][nf] partial over this lane's 16 o's
      #pragma unroll
      for (int p = 0; p < 8; ++p)
        #pragma unroll
        for (int mi = 0; mi < 4; ++mi) {
          const f32x4 w4 = *(const f32x4*)(W2 + p * NC + w * 64 + mi * 16 + lg * 4);
          #pragma unroll
          for (int nf = 0; nf < 4; ++nf)
            pd[p][nf] += w4[0] * acc1[mi][nf][0] + w4[1] * acc1[mi][nf][1]
                       + w4[2] * acc1[mi][nf][2] + w4[3] * acc1[mi][nf][3];
        }
      // reduce over the 4 k-groups (lanes ^16, ^32 share the same s)
      #pragma unroll
      for (int p = 0; p < 8; ++p)
        #pragma unroll
        for (int nf = 0; nf < 4; ++nf) {
          pd[p][nf] += __shfl_xor(pd[p][nf], 16, 64);
          pd[p][nf] += __shfl_xor(pd[p][nf], 32, 64);
        }
      float* dpart = (float*)(sm + DP_OFF);
      if (lg == 0) {
        #pragma unroll
        for (int p = 0; p < 8; ++p)
          #pragma unroll
          for (int nf = 0; nf < 4; ++nf)
            dpart[w * 512 + p * 64 + nf * 16 + ln] = pd[p][nf];
      }
    }
    __syncthreads();

    // ---- combine waves + sigmoid -> mls ----
    {
      const float* dp = (const float*)(sm + DP_OFF);
      float* mls = (float*)(sm + MLS_OFF);
      #pragma unroll
      for (int it = 0; it < 2; ++it) {
        const int id = it * 256 + t;
        const int p = id >> 6, s = id & 63;
        float d = b2[p];
        #pragma unroll
        for (int ww = 0; ww < 4; ++ww) d += dp[ww * 512 + p * 64 + s];
        const float m = 1.0f / (1.0f + __expf(-d));
        mls[s * 16 + ((s >> 4) & 1) * 4 + p] = m;
      }
    }
    __syncthreads();

    // ---- vec contraction from LDS: accv[c-sub][p] += x[c][s]*m[p][s] ----
    {
      const float* mlsr = (const float*)(sm + MLS_OFF);
      #pragma unroll 4
      for (int i = 0; i < 16; ++i) {
        const int s = sq * 16 + i;
        const float* mrow = mlsr + s * 16 + ((s >> 4) & 1) * 4;
        const f32x4 m0 = *(const f32x4*)mrow;
        const f32x4 m1 = *(const f32x4*)(mrow + 4);
        const char* xrow = sm + s * XS_PITCH + ((cb * 8) ^ SWZ(s));
        const f16x4 h4 = *(const f16x4*)xrow;
        const f16x4 l4 = *(const f16x4*)(xrow + XS_LO);
        #pragma unroll
        for (int j = 0; j < 4; ++j) {
          const float xf = (float)h4[j] + (float)l4[j] * (1.0f / 512.0f);
          #pragma unroll
          for (int p = 0; p < 4; ++p) {
            accv[j][p]     += xf * m0[p];
            accv[j][p + 4] += xf * m1[p];
          }
        }
        #pragma unroll
        for (int p = 0; p < 4; ++p) { smac[p] += m0[p]; smac[p + 4] += m1[p]; }
      }
    }
  }  // tt

  // ---- butterfly over the 4 sq lanes; write per-tile-group partials ----
  #pragma unroll
  for (int j = 0; j < 4; ++j)
    #pragma unroll
    for (int p = 0; p < 8; ++p) {
      accv[j][p] += __shfl_xor(accv[j][p], 1, 64);
      accv[j][p] += __shfl_xor(accv[j][p], 2, 64);
    }
  #pragma unroll
  for (int p = 0; p < 8; ++p) {
    smac[p] += __shfl_xor(smac[p], 1, 64);
    smac[p] += __shfl_xor(smac[p], 2, 64);
  }

  f32x4 o0, o1;
  #pragma unroll
  for (int p = 0; p < 8; ++p) {
    const float v01 = (sq & 1) ? accv[1][p] : accv[0][p];
    const float v23 = (sq & 1) ? accv[3][p] : accv[2][p];
    const float v = (sq & 2) ? v23 : v01;
    if (p < 4) o0[p] = v; else o1[p - 4] = v;
  }
  // lane t writes channel c == t (c = 4*(t>>2) + (t&3) = t): coalesced 32B/lane
  float* dst = pvec_t + (((size_t)(b * 16 + tg) * 256) + t) * 8;
  *(f32x4*)dst = o0;
  *(f32x4*)(dst + 4) = o1;
  if (t == 0) {
    f32x4 s0, s1;
    #pragma unroll
    for (int p = 0; p < 4; ++p) { s0[p] = smac[p]; s1[p] = smac[p + 4]; }
    float* d2 = psw_t + (size_t)(b * 16 + tg) * 8;
    *(f32x4*)d2 = s0;
    *(f32x4*)(d2 + 4) = s1;
  }
}

// final reduce over 16 tile-groups + divide by sum_w; out flat = (B, C, P)
// (torch's view(B,C*P).reshape(B,P,-1) is a raw reshape: flat order unchanged)
__global__ __launch_bounds__(256) void k_reduce(
    const float* __restrict__ pvec, const float* __restrict__ psw,
    float* __restrict__ out) {
  const int idx = blockIdx.x * 256 + threadIdx.x;  // 65536
  const int b = idx >> 11;
  const int cp = idx & 2047;  // c*8+p
  const int p = idx & 7;
  float v = 0.f, sw = 1e-12f;
  #pragma unroll
  for (int ch = 0; ch < 16; ++ch) {
    v += pvec[((size_t)(b * 16 + ch)) * 2048 + cp];
    sw += psw[((size_t)(b * 16 + ch)) * 8 + p];
  }
  out[idx] = v / sw;
}

extern "C" void kernel_launch(void* const* d_in, const int* in_sizes, int n_in,
                              void* d_out, int out_size, void* d_ws, size_t ws_size,
                              hipStream_t stream) {
  const float* x     = (const float*)d_in[0];
  const float* W1    = (const float*)d_in[1];
  const float* b1    = (const float*)d_in[2];
  const float* gamma = (const float*)d_in[3];
  const float* beta  = (const float*)d_in[4];
  const float* mean  = (const float*)d_in[5];
  const float* var   = (const float*)d_in[6];
  const float* W2    = (const float*)d_in[7];
  const float* b2    = (const float*)d_in[8];

  char* ws = (char*)d_ws;
  f16* Ah      = (f16*)(ws + AH_OFF);
  f16* Al      = (f16*)(ws + AL_OFF);
  float* cvec  = (float*)(ws + CV_OFF);
  float* pvec_t = (float*)(ws + PV_OFF);
  float* psw_t  = (float*)(ws + PS_OFF);
  float* out   = (float*)d_out;

  (void)hipFuncSetAttribute((const void*)k_fused,
                            hipFuncAttributeMaxDynamicSharedMemorySize,
                            SMEM_BYTES);

  k_prep<<<256, 256, 0, stream>>>(W1, b1, gamma, beta, mean, var, Ah, Al, cvec);
  k_fused<<<512, 256, SMEM_BYTES, stream>>>(x, Ah, Al, cvec, W2, b2, pvec_t, psw_t);
  k_reduce<<<256, 256, 0, stream>>>(pvec_t, psw_t, out);
}

// Round 5
// 355.020 us; speedup vs baseline: 1.0206x; 1.0206x over previous
//
#include <hip/hip_runtime.h>

typedef _Float16 f16;
typedef f16 f16x8 __attribute__((ext_vector_type(8)));
typedef f16 f16x4 __attribute__((ext_vector_type(4)));
typedef float f32x4 __attribute__((ext_vector_type(4)));

#define NB 32
#define NC 256
#define NP 8
#define NHW 4096

// ---- workspace byte offsets ----
#define AH_OFF 0u         // A_hi f16 [256][256]
#define AL_OFF 131072u    // A_lo f16 [256][256] (x512 scaled)
#define CV_OFF 262144u    // cvec f32 [256]
#define PV_OFF 263168u    // pvec_t f32 [B][16][256][8] = 4 MB
#define PS_OFF 4457472u   // psw_t  f32 [B][16][8]
// end ~4.47 MB

// ---- k_fused LDS geometry (bytes) ----
#define XS_PITCH 528      // per s-row: 256 f16 data + pad; 16B-aligned rows
#define XS_LO    33792    // lo region base (64 * 528)
#define DP_OFF   67584    // dpart f32 [4][8][64] = 8 KB
#define MLS_OFF  75776    // mls f32: 64 rows * 16 dwords = 4 KB
#define SMEM_BYTES 79872  // 2 blocks/CU (159744 <= 160 KiB)

#define SWZ(s) ((((s) >> 2) & 7) << 4)   // 16B-granular XOR swizzle key

#define MFMA16(a, b, c) __builtin_amdgcn_mfma_f32_16x16x32_f16(a, b, c, 0, 0, 0)

// Fold BN into conv1; split folded weight into f16 hi + (lo*512).
__global__ __launch_bounds__(256) void k_prep(
    const float* __restrict__ W1, const float* __restrict__ b1,
    const float* __restrict__ gamma, const float* __restrict__ beta,
    const float* __restrict__ mean, const float* __restrict__ var,
    f16* __restrict__ Ah, f16* __restrict__ Al, float* __restrict__ cvec) {
  const int o = blockIdx.x;
  const int k = threadIdx.x;
  const float inv = gamma[o] * rsqrtf(var[o] + 1e-5f);
  const float a = W1[o * NC + k] * inv;
  const f16 hi = (f16)a;
  Ah[o * NC + k] = hi;
  Al[o * NC + k] = (f16)((a - (float)hi) * 512.0f);
  if (k == 0) cvec[o] = (b1[o] - mean[o]) * inv + beta[o];
}

// Fused: conv1(MFMA f16 hi/lo)+BN+ReLU + conv2+sigmoid + vec contraction.
// Block = (batch, tile-group of 4 x 64-spatial tiles); 4 waves; 2 blocks/CU.
// waves_per_eu(2,2): LDS (dynamic, invisible to the allocator) caps us at
// 2 blocks/CU = 2 waves/EU anyway; pinning it gives the full 256-VGPR budget
// and stops the allocator from targeting 4 waves/EU (r4: 128 VGPRs -> 250 MB
// of scratch spill traffic, 222 us).
__global__ __launch_bounds__(256)
__attribute__((amdgpu_waves_per_eu(2, 2)))
void k_fused(
    const float* __restrict__ x, const f16* __restrict__ Ah,
    const f16* __restrict__ Al, const float* __restrict__ cvec,
    const float* __restrict__ W2, const float* __restrict__ b2,
    float* __restrict__ pvec_t, float* __restrict__ psw_t) {
  extern __shared__ __align__(16) char sm[];
  const int b  = blockIdx.x >> 4;
  const int tg = blockIdx.x & 15;
  const int t  = threadIdx.x;
  const int w    = t >> 6;   // wave: o-slice base w*64
  const int lane = t & 63;
  const int lg = lane >> 4;  // k-group
  const int ln = lane & 15;  // m (A-row) / n (s-col)
  const int cb = t >> 2;     // vec phase: channel block (4 ch)
  const int sq = t & 3;      // vec phase: s quarter (16 s)

  float accv[4][8];          // vec partials [c-sub][p], persist across tiles
  float smac[8];             // sum_w partials
  #pragma unroll
  for (int j = 0; j < 4; ++j)
    #pragma unroll
    for (int p = 0; p < 8; ++p) accv[j][p] = 0.f;
  #pragma unroll
  for (int p = 0; p < 8; ++p) smac[p] = 0.f;

  for (int tt = 0; tt < 4; ++tt) {
    const int hw0 = (tg * 4 + tt) * 64;
    __syncthreads();  // protect xs/mls/dpart from previous iteration's readers

    // ---- stage x tile: [256c][64s] f32 -> LDS transposed f16 hi/lo, swizzled ----
    {
      const float* xb = x + (size_t)b * NC * NHW + hw0;
      #pragma unroll
      for (int i = 0; i < 4; ++i) {
        const int id = i * 256 + t;
        const int cbs = id >> 4;   // channel block (4 ch)
        const int sb  = id & 15;   // spatial block (4 s)
        const float* r0 = xb + (size_t)(cbs * 4) * NHW + sb * 4;
        const float4 v0 = *(const float4*)(r0);
        const float4 v1 = *(const float4*)(r0 + NHW);
        const float4 v2 = *(const float4*)(r0 + 2 * NHW);
        const float4 v3 = *(const float4*)(r0 + 3 * NHW);
        #pragma unroll
        for (int j = 0; j < 4; ++j) {
          const float e0 = ((const float*)&v0)[j];
          const float e1 = ((const float*)&v1)[j];
          const float e2 = ((const float*)&v2)[j];
          const float e3 = ((const float*)&v3)[j];
          const f16 h0 = (f16)e0, h1 = (f16)e1, h2 = (f16)e2, h3 = (f16)e3;
          const f16 l0 = (f16)((e0 - (float)h0) * 512.0f);
          const f16 l1 = (f16)((e1 - (float)h1) * 512.0f);
          const f16 l2 = (f16)((e2 - (float)h2) * 512.0f);
          const f16 l3 = (f16)((e3 - (float)h3) * 512.0f);
          const int s = sb * 4 + j;
          char* dst = sm + s * XS_PITCH + ((cbs * 8) ^ SWZ(s));
          *(f16x4*)dst = (f16x4){h0, h1, h2, h3};
          *(f16x4*)(dst + XS_LO) = (f16x4){l0, l1, l2, l3};
        }
      }
    }
    __syncthreads();

    // ---- GEMM: h[o][s] = sum_c A[o][c]*x[c][s]; wave owns o in [w*64, w*64+64) ----
    f32x4 acc1[4][4] = {};   // hi*hi
    f32x4 acc2[4][4] = {};   // hi*lo + lo*hi (x512)
    #pragma unroll 1
    for (int k0 = 0; k0 < 8; ++k0) {
      // staggered loads: peak live fragments ~48 VGPRs instead of 64
      f16x8 ah[4], xh[4], xo[4];
      #pragma unroll
      for (int mi = 0; mi < 4; ++mi) {
        const size_t off = (size_t)((w * 64 + mi * 16 + ln) * NC + k0 * 32 + lg * 8);
        ah[mi] = *(const f16x8*)(Ah + off);
      }
      #pragma unroll
      for (int nf = 0; nf < 4; ++nf) {
        const int s = nf * 16 + ln;
        xh[nf] = *(const f16x8*)(sm + s * XS_PITCH + ((k0 * 64 + lg * 16) ^ SWZ(s)));
      }
      #pragma unroll
      for (int mi = 0; mi < 4; ++mi)
        #pragma unroll
        for (int nf = 0; nf < 4; ++nf)
          acc1[mi][nf] = MFMA16(ah[mi], xh[nf], acc1[mi][nf]);

      #pragma unroll
      for (int nf = 0; nf < 4; ++nf) {
        const int s = nf * 16 + ln;
        xo[nf] = *(const f16x8*)(sm + XS_LO + s * XS_PITCH + ((k0 * 64 + lg * 16) ^ SWZ(s)));
      }
      #pragma unroll
      for (int mi = 0; mi < 4; ++mi)
        #pragma unroll
        for (int nf = 0; nf < 4; ++nf)
          acc2[mi][nf] = MFMA16(ah[mi], xo[nf], acc2[mi][nf]);

      #pragma unroll
      for (int mi = 0; mi < 4; ++mi) {
        const size_t off = (size_t)((w * 64 + mi * 16 + ln) * NC + k0 * 32 + lg * 8);
        xo[mi] = *(const f16x8*)(Al + off);   // reuse xo regs for Al frags
      }
      #pragma unroll
      for (int mi = 0; mi < 4; ++mi)
        #pragma unroll
        for (int nf = 0; nf < 4; ++nf)
          acc2[mi][nf] = MFMA16(xo[mi], xh[nf], acc2[mi][nf]);
    }

    // ---- bias + ReLU in-register; conv2 partials per lane ----
    {
      f32x4 cv[4];
      #pragma unroll
      for (int mi = 0; mi < 4; ++mi)
        cv[mi] = *(const f32x4*)(cvec + w * 64 + mi * 16 + lg * 4);
      #pragma unroll
      for (int mi = 0; mi < 4; ++mi)
        #pragma unroll
        for (int nf = 0; nf < 4; ++nf)
          #pragma unroll
          for (int r = 0; r < 4; ++r) {
            const float v = acc1[mi][nf][r] + acc2[mi][nf][r] * (1.0f / 512.0f) + cv[mi][r];
            acc1[mi][nf][r] = v > 0.0f ? v : 0.0f;  // h
          }

      float pd[8][4] = {};  // [p][nf] partial over this lane's 16 o's
      #pragma unroll
      for (int p = 0; p < 8; ++p)
        #pragma unroll
        for (int mi = 0; mi < 4; ++mi) {
          const f32x4 w4 = *(const f32x4*)(W2 + p * NC + w * 64 + mi * 16 + lg * 4);
          #pragma unroll
          for (int nf = 0; nf < 4; ++nf)
            pd[p][nf] += w4[0] * acc1[mi][nf][0] + w4[1] * acc1[mi][nf][1]
                       + w4[2] * acc1[mi][nf][2] + w4[3] * acc1[mi][nf][3];
        }
      // reduce over the 4 k-groups (lanes ^16, ^32 share the same s)
      #pragma unroll
      for (int p = 0; p < 8; ++p)
        #pragma unroll
        for (int nf = 0; nf < 4; ++nf) {
          pd[p][nf] += __shfl_xor(pd[p][nf], 16, 64);
          pd[p][nf] += __shfl_xor(pd[p][nf], 32, 64);
        }
      float* dpart = (float*)(sm + DP_OFF);
      if (lg == 0) {
        #pragma unroll
        for (int p = 0; p < 8; ++p)
          #pragma unroll
          for (int nf = 0; nf < 4; ++nf)
            dpart[w * 512 + p * 64 + nf * 16 + ln] = pd[p][nf];
      }
    }
    __syncthreads();

    // ---- combine waves + sigmoid -> mls ----
    {
      const float* dp = (const float*)(sm + DP_OFF);
      float* mls = (float*)(sm + MLS_OFF);
      #pragma unroll
      for (int it = 0; it < 2; ++it) {
        const int id = it * 256 + t;
        const int p = id >> 6, s = id & 63;
        float d = b2[p];
        #pragma unroll
        for (int ww = 0; ww < 4; ++ww) d += dp[ww * 512 + p * 64 + s];
        const float m = 1.0f / (1.0f + __expf(-d));
        mls[s * 16 + ((s >> 4) & 1) * 4 + p] = m;
      }
    }
    __syncthreads();

    // ---- vec contraction from LDS: accv[c-sub][p] += x[c][s]*m[p][s] ----
    {
      const float* mlsr = (const float*)(sm + MLS_OFF);
      #pragma unroll 4
      for (int i = 0; i < 16; ++i) {
        const int s = sq * 16 + i;
        const float* mrow = mlsr + s * 16 + ((s >> 4) & 1) * 4;
        const f32x4 m0 = *(const f32x4*)mrow;
        const f32x4 m1 = *(const f32x4*)(mrow + 4);
        const char* xrow = sm + s * XS_PITCH + ((cb * 8) ^ SWZ(s));
        const f16x4 h4 = *(const f16x4*)xrow;
        const f16x4 l4 = *(const f16x4*)(xrow + XS_LO);
        #pragma unroll
        for (int j = 0; j < 4; ++j) {
          const float xf = (float)h4[j] + (float)l4[j] * (1.0f / 512.0f);
          #pragma unroll
          for (int p = 0; p < 4; ++p) {
            accv[j][p]     += xf * m0[p];
            accv[j][p + 4] += xf * m1[p];
          }
        }
        #pragma unroll
        for (int p = 0; p < 4; ++p) { smac[p] += m0[p]; smac[p + 4] += m1[p]; }
      }
    }
  }  // tt

  // ---- butterfly over the 4 sq lanes; write per-tile-group partials ----
  #pragma unroll
  for (int j = 0; j < 4; ++j)
    #pragma unroll
    for (int p = 0; p < 8; ++p) {
      accv[j][p] += __shfl_xor(accv[j][p], 1, 64);
      accv[j][p] += __shfl_xor(accv[j][p], 2, 64);
    }
  #pragma unroll
  for (int p = 0; p < 8; ++p) {
    smac[p] += __shfl_xor(smac[p], 1, 64);
    smac[p] += __shfl_xor(smac[p], 2, 64);
  }

  f32x4 o0, o1;
  #pragma unroll
  for (int p = 0; p < 8; ++p) {
    const float v01 = (sq & 1) ? accv[1][p] : accv[0][p];
    const float v23 = (sq & 1) ? accv[3][p] : accv[2][p];
    const float v = (sq & 2) ? v23 : v01;
    if (p < 4) o0[p] = v; else o1[p - 4] = v;
  }
  // lane t writes channel c == t (c = 4*(t>>2) + (t&3) = t): coalesced 32B/lane
  float* dst = pvec_t + (((size_t)(b * 16 + tg) * 256) + t) * 8;
  *(f32x4*)dst = o0;
  *(f32x4*)(dst + 4) = o1;
  if (t == 0) {
    f32x4 s0, s1;
    #pragma unroll
    for (int p = 0; p < 4; ++p) { s0[p] = smac[p]; s1[p] = smac[p + 4]; }
    float* d2 = psw_t + (size_t)(b * 16 + tg) * 8;
    *(f32x4*)d2 = s0;
    *(f32x4*)(d2 + 4) = s1;
  }
}

// final reduce over 16 tile-groups + divide by sum_w; out flat = (B, C, P)
// (torch's view(B,C*P).reshape(B,P,-1) is a raw reshape: flat order unchanged)
__global__ __launch_bounds__(256) void k_reduce(
    const float* __restrict__ pvec, const float* __restrict__ psw,
    float* __restrict__ out) {
  const int idx = blockIdx.x * 256 + threadIdx.x;  // 65536
  const int b = idx >> 11;
  const int cp = idx & 2047;  // c*8+p
  const int p = idx & 7;
  float v = 0.f, sw = 1e-12f;
  #pragma unroll
  for (int ch = 0; ch < 16; ++ch) {
    v += pvec[((size_t)(b * 16 + ch)) * 2048 + cp];
    sw += psw[((size_t)(b * 16 + ch)) * 8 + p];
  }
  out[idx] = v / sw;
}

extern "C" void kernel_launch(void* const* d_in, const int* in_sizes, int n_in,
                              void* d_out, int out_size, void* d_ws, size_t ws_size,
                              hipStream_t stream) {
  const float* x     = (const float*)d_in[0];
  const float* W1    = (const float*)d_in[1];
  const float* b1    = (const float*)d_in[2];
  const float* gamma = (const float*)d_in[3];
  const float* beta  = (const float*)d_in[4];
  const float* mean  = (const float*)d_in[5];
  const float* var   = (const float*)d_in[6];
  const float* W2    = (const float*)d_in[7];
  const float* b2    = (const float*)d_in[8];

  char* ws = (char*)d_ws;
  f16* Ah      = (f16*)(ws + AH_OFF);
  f16* Al      = (f16*)(ws + AL_OFF);
  float* cvec  = (float*)(ws + CV_OFF);
  float* pvec_t = (float*)(ws + PV_OFF);
  float* psw_t  = (float*)(ws + PS_OFF);
  float* out   = (float*)d_out;

  (void)hipFuncSetAttribute((const void*)k_fused,
                            hipFuncAttributeMaxDynamicSharedMemorySize,
                            SMEM_BYTES);

  k_prep<<<256, 256, 0, stream>>>(W1, b1, gamma, beta, mean, var, Ah, Al, cvec);
  k_fused<<<512, 256, SMEM_BYTES, stream>>>(x, Ah, Al, cvec, W2, b2, pvec_t, psw_t);
  k_reduce<<<256, 256, 0, stream>>>(pvec_t, psw_t, out);
}